// Round 6
// baseline (414.512 us; speedup 1.0000x reference)
//
#include <hip/hip_runtime.h>

#define DEVFN __device__ __forceinline__

typedef __bf16 bf16x8 __attribute__((ext_vector_type(8)));
typedef float f32x4 __attribute__((ext_vector_type(4)));
typedef unsigned short u16;

// B=2, T=S=2048, D=1024, H=16, DH=64
// Scales folded into weights: Wq *= 0.125*log2(e), Wk *= 0.125  =>
// score_log2e = q'.k' + q'.L  ; softmax done in exp2 domain.

DEVFN u16 f2bf(float f) {
  unsigned u = __builtin_bit_cast(unsigned, f);
  u += 0x7FFFu + ((u >> 16) & 1u);
  return (u16)(u >> 16);
}

DEVFN float bf2f(u16 v) {
  return __builtin_bit_cast(float, (unsigned)v << 16);
}

DEVFN f32x4 mfma16(bf16x8 a, bf16x8 b, f32x4 c) {
  return __builtin_amdgcn_mfma_f32_16x16x32_bf16(a, b, c, 0, 0, 0);
}

DEVFN void gl16(const u16* g, u16* l) {
  __builtin_amdgcn_global_load_lds(
      (const __attribute__((address_space(1))) unsigned int*)g,
      (__attribute__((address_space(3))) unsigned int*)l, 16, 0, 0);
}

// ---------------- LayerNorm: x[4096,1024] -> xn (f32, into d_out) + xn bf16 ----------------
__global__ __launch_bounds__(256) void ln_kernel(const float* __restrict__ x,
                                                 const float* __restrict__ gamma,
                                                 const float* __restrict__ beta,
                                                 float* __restrict__ xn,
                                                 u16* __restrict__ xnb) {
  int row = blockIdx.x;
  int tid = threadIdx.x;
  const float4* xr = (const float4*)(x + (size_t)row * 1024);
  float4 v = xr[tid];
  float s = v.x + v.y + v.z + v.w;
  float q = v.x * v.x + v.y * v.y + v.z * v.z + v.w * v.w;
#pragma unroll
  for (int m = 1; m < 64; m <<= 1) {
    s += __shfl_xor(s, m);
    q += __shfl_xor(q, m);
  }
  __shared__ float rs[4], rq[4];
  int w = tid >> 6;
  if ((tid & 63) == 0) { rs[w] = s; rq[w] = q; }
  __syncthreads();
  s = rs[0] + rs[1] + rs[2] + rs[3];
  q = rq[0] + rq[1] + rq[2] + rq[3];
  float mean = s * (1.0f / 1024.0f);
  float var = q * (1.0f / 1024.0f) - mean * mean;
  float inv = rsqrtf(var + 1e-5f);
  float4 g = ((const float4*)gamma)[tid];
  float4 bt = ((const float4*)beta)[tid];
  float4 o;
  o.x = (v.x - mean) * inv * g.x + bt.x;
  o.y = (v.y - mean) * inv * g.y + bt.y;
  o.z = (v.z - mean) * inv * g.z + bt.z;
  o.w = (v.w - mean) * inv * g.w + bt.w;
  ((float4*)(xn + (size_t)row * 1024))[tid] = o;
  ushort4 ob;
  ob.x = f2bf(o.x); ob.y = f2bf(o.y); ob.z = f2bf(o.z); ob.w = f2bf(o.w);
  ((ushort4*)(xnb + (size_t)row * 1024))[tid] = ob;
}

// ---------------- f32 -> bf16 convert (vectorized by 4) ----------------
__global__ __launch_bounds__(256) void cvt_kernel(const float* __restrict__ in,
                                                  u16* __restrict__ out, int n4) {
  int i = blockIdx.x * 256 + threadIdx.x;
  if (i < n4) {
    float4 v = ((const float4*)in)[i];
    ushort4 o;
    o.x = f2bf(v.x); o.y = f2bf(v.y); o.z = f2bf(v.z); o.w = f2bf(v.w);
    ((ushort4*)out)[i] = o;
  }
}

// ---------------- 4x W [1024,1024] f32 -> Wall[z] bf16 transposed (scaled) ----------------
__global__ __launch_bounds__(256) void transW_kernel(const float* __restrict__ W0,
                                                     const float* __restrict__ W1,
                                                     const float* __restrict__ W2,
                                                     const float* __restrict__ W3,
                                                     u16* __restrict__ Wall) {
  __shared__ float tile[32][33];
  int z = blockIdx.z;
  const float* W = (z == 0) ? W0 : (z == 1) ? W1 : (z == 2) ? W2 : W3;
  float scale = (z == 0) ? 0.18033688011112042f : (z == 1) ? 0.125f : 1.0f;
  u16* Wt = Wall + (size_t)z * 1048576;
  int tx = threadIdx.x, ty = threadIdx.y;
  int x = blockIdx.x * 32 + tx;
  int y0 = blockIdx.y * 32;
#pragma unroll
  for (int j = 0; j < 32; j += 8)
    tile[ty + j][tx] = W[(size_t)(y0 + ty + j) * 1024 + x];
  __syncthreads();
#pragma unroll
  for (int j = 0; j < 32; j += 8)
    Wt[(size_t)(blockIdx.x * 32 + ty + j) * 1024 + y0 + tx] = f2bf(tile[tx][ty + j] * scale);
}

// ---------------- shared GEMM core: 128x64 tile, K=1024, gload_lds + XOR swizzle ----------------
DEVFN void gemm_core(const u16* __restrict__ A, const u16* __restrict__ Bt,
                     u16* Ab, u16* Bb, int row0, int n0, int tid,
                     f32x4 (&acc)[2][4]) {
  int lane = tid & 63, wv = tid >> 6;
  int l16 = lane & 15, lhi = lane >> 4;
  int r8 = lane >> 3, c8 = lane & 7;
  int cx = ((c8 ^ r8) << 3);           // pre-swizzled source column (elements)
  int swz = (l16 & 7) << 3;            // read-side XOR (elements)

  auto stage = [&](int k0) {
#pragma unroll
    for (int i = 0; i < 4; ++i) {
      int rowb = wv * 32 + i * 8;
      gl16(&A[(size_t)(row0 + rowb + r8) * 1024 + k0 + cx], &Ab[rowb * 64]);
    }
#pragma unroll
    for (int i = 0; i < 2; ++i) {
      int rowb = wv * 16 + i * 8;
      gl16(&Bt[(size_t)(n0 + rowb + r8) * 1024 + k0 + cx], &Bb[rowb * 64]);
    }
  };

  stage(0);
  asm volatile("s_waitcnt vmcnt(0)" ::: "memory");
  __syncthreads();
  for (int kk = 0; kk < 16; ++kk) {
    __builtin_amdgcn_s_setprio(1);
#pragma unroll
    for (int ks = 0; ks < 2; ++ks) {
      bf16x8 af[2], bfr[4];
#pragma unroll
      for (int mi = 0; mi < 2; ++mi) {
        int row = wv * 32 + mi * 16 + l16;
        af[mi] = *(const bf16x8*)&Ab[row * 64 + ((ks * 32 + lhi * 8) ^ swz)];
      }
#pragma unroll
      for (int ni = 0; ni < 4; ++ni) {
        int row = ni * 16 + l16;
        bfr[ni] = *(const bf16x8*)&Bb[row * 64 + ((ks * 32 + lhi * 8) ^ swz)];
      }
#pragma unroll
      for (int mi = 0; mi < 2; ++mi)
#pragma unroll
        for (int ni = 0; ni < 4; ++ni)
          acc[mi][ni] = mfma16(af[mi], bfr[ni], acc[mi][ni]);
    }
    __builtin_amdgcn_s_setprio(0);
    if (kk < 15) {
      __syncthreads();
      stage((kk + 1) * 64);
      asm volatile("s_waitcnt vmcnt(0)" ::: "memory");
      __syncthreads();
    }
  }
}

// ---------------- QKV projections in one launch (z = 0,1,2) ----------------
// z=0: Q = xn@Wq' -> [B,H,T,64]; z=1: K -> [B,H,S,64]; z=2: V -> [B,H,64,S] (transposed!)
__global__ __launch_bounds__(256, 4) void qkv_kernel(const u16* __restrict__ xnb,
                                                     const u16* __restrict__ ctxb,
                                                     const u16* __restrict__ Wall,
                                                     u16* __restrict__ qb,
                                                     u16* __restrict__ kb,
                                                     u16* __restrict__ vtb) {
  __shared__ __align__(16) u16 Ab[128 * 64];
  __shared__ __align__(16) u16 Bb[64 * 64];
  int z = blockIdx.z;
  const u16* A = (z == 0) ? xnb : ctxb;
  const u16* Bt = Wall + (size_t)z * 1048576;
  int row0 = blockIdx.x * 128, n0 = blockIdx.y * 64;
  f32x4 acc[2][4] = {};
  gemm_core(A, Bt, Ab, Bb, row0, n0, threadIdx.x, acc);
  int tid = threadIdx.x, lane = tid & 63, wv = tid >> 6;
  int l16 = lane & 15, lhi = lane >> 4;
  u16* qk = (z == 0) ? qb : kb;
#pragma unroll
  for (int mi = 0; mi < 2; ++mi)
#pragma unroll
    for (int ni = 0; ni < 4; ++ni)
#pragma unroll
      for (int r = 0; r < 4; ++r) {
        int m = row0 + wv * 32 + mi * 16 + lhi * 4 + r;
        int n = n0 + ni * 16 + l16;
        int b = m >> 11, t = m & 2047, h = n >> 6, dh = n & 63;
        u16 val = f2bf(acc[mi][ni][r]);
        if (z < 2)
          qk[(size_t)((b * 16 + h) * 2048 + t) * 64 + dh] = val;
        else
          vtb[(size_t)((b * 16 + h) * 64 + dh) * 2048 + t] = val;
      }
}

// ---------------- output projection + bias + residual ----------------
__global__ __launch_bounds__(256, 4) void oproj_kernel(const u16* __restrict__ attnb,
                                                       const u16* __restrict__ Wall,
                                                       const float* __restrict__ bias,
                                                       const float* __restrict__ resid,
                                                       float* __restrict__ outF) {
  __shared__ __align__(16) u16 Ab[128 * 64];
  __shared__ __align__(16) u16 Bb[64 * 64];
  const u16* Bt = Wall + (size_t)3 * 1048576;
  int row0 = blockIdx.x * 128, n0 = blockIdx.y * 64;
  f32x4 acc[2][4] = {};
  gemm_core(attnb, Bt, Ab, Bb, row0, n0, threadIdx.x, acc);
  int tid = threadIdx.x, lane = tid & 63, wv = tid >> 6;
  int l16 = lane & 15, lhi = lane >> 4;
#pragma unroll
  for (int mi = 0; mi < 2; ++mi)
#pragma unroll
    for (int ni = 0; ni < 4; ++ni)
#pragma unroll
      for (int r = 0; r < 4; ++r) {
        int m = row0 + wv * 32 + mi * 16 + lhi * 4 + r;
        int n = n0 + ni * 16 + l16;
        outF[(size_t)m * 1024 + n] = acc[mi][ni][r] + bias[n] + resid[(size_t)m * 1024 + n];
      }
}

// ---------------- flash attention, KV-split x2 (flash-decoding) ----------------
// Qg,Kg: [B,H,2048,64] bf16 (scaled). Vtg: [B,H,64,2048] bf16. Lb: [4095,64] bf16.
// Each block: 64 q-rows, 16 KV tiles (1024 keys). Writes UNNORMALIZED O (bf16)
// + per-row (m, l) to pbuf/mlb; combine_kernel merges the two halves.
__global__ __launch_bounds__(256, 6) void flash_kernel(
    const u16* __restrict__ Qg, const u16* __restrict__ Kg,
    const u16* __restrict__ Vtg, const u16* __restrict__ Lb,
    u16* __restrict__ pbuf, float* __restrict__ mlb) {
  constexpr int T = 2048, H = 16;
  int p = blockIdx.x;
  int bid = (p & 7) * 256 + (p >> 3);  // XCD-contiguous mapping (grid=2048, 8 XCDs)
  int half = bid & 1;
  int cid = bid >> 1;
  int qb = cid & 31, h = (cid >> 5) & 15, b = cid >> 9;
  int st = half * 16;  // first KV tile index
  int tid = threadIdx.x;
  int lane = tid & 63, w = tid >> 6;
  int l16 = lane & 15, lhi = lane >> 4;

  __shared__ __align__(16) u16 Klds[64 * 64];     // 8 KB
  __shared__ __align__(16) u16 Vt[64 * 64];       // 8 KB
  __shared__ __align__(16) u16 Plds[4][16 * 64];  // 8 KB (XOR-swizzled)

  const u16* qbase = Qg + (size_t)(b * H + h) * T * 64;
  const u16* kbase = Kg + (size_t)(b * H + h) * T * 64;
  const u16* vtbase = Vtg + (size_t)(b * H + h) * 64 * 2048;

  int i0w = qb * 64 + w * 16;
  bf16x8 aq[2];
  aq[0] = *(const bf16x8*)&qbase[(i0w + l16) * 64 + lhi * 8];
  aq[1] = *(const bf16x8*)&qbase[(i0w + l16) * 64 + 32 + lhi * 8];

  f32x4 accO[4] = {};
  float mrun[4], lsum[4];
#pragma unroll
  for (int r = 0; r < 4; ++r) { mrun[r] = -1e30f; lsum[r] = 0.0f; }

  int bandbase = T - 16 - i0w;

  int r8 = lane >> 3, c8 = lane & 7;
  int cx = ((c8 ^ r8) << 3);
  int swz = (l16 & 7) << 3;

  auto stage = [&](int j0) {
#pragma unroll
    for (int i = 0; i < 2; ++i) {
      int rowb = w * 16 + i * 8;
      gl16(&kbase[(size_t)(j0 + rowb + r8) * 64 + cx], &Klds[rowb * 64]);
    }
#pragma unroll
    for (int i = 0; i < 2; ++i) {
      int rowb = w * 16 + i * 8;
      gl16(&vtbase[(size_t)(rowb + r8) * 2048 + j0 + cx], &Vt[rowb * 64]);
    }
  };

  // E-carry preamble: eC = E[., colE 0..15] of the first tile of this half
  f32x4 eC = {};
#pragma unroll
  for (int ks = 0; ks < 2; ++ks) {
    int u = bandbase + st * 64 + l16;
    u = min(max(u, 0), 2 * T - 2);
    bf16x8 bl = *(const bf16x8*)&Lb[(size_t)u * 64 + ks * 32 + lhi * 8];
    eC = mfma16(aq[ks], bl, eC);
  }

  const float THR = 11.541560327111707f;  // 8 * log2(e)

  for (int kt = st; kt < st + 16; ++kt) {
    int j0 = kt * 64, bstart = bandbase + j0;
    // issue stage for THIS tile, hide the drain under the E-term MFMAs
    stage(j0);

    f32x4 accE[5];
    accE[0] = eC;
#pragma unroll
    for (int c = 1; c < 5; ++c) accE[c] = f32x4{0.f, 0.f, 0.f, 0.f};
#pragma unroll
    for (int ks = 0; ks < 2; ++ks) {
      bf16x8 bl[4];
#pragma unroll
      for (int c = 1; c < 5; ++c) {
        int u = bstart + c * 16 + l16;
        u = min(max(u, 0), 2 * T - 2);
        bl[c - 1] = *(const bf16x8*)&Lb[(size_t)u * 64 + ks * 32 + lhi * 8];
      }
#pragma unroll
      for (int c = 1; c < 5; ++c) accE[c] = mfma16(aq[ks], bl[c - 1], accE[c]);
    }
    eC = accE[4];

    __syncthreads();  // drains vmcnt(0): gl16 latency mostly elapsed under E

    // QK^T
    f32x4 accS[4] = {};
    __builtin_amdgcn_s_setprio(1);
#pragma unroll
    for (int ks = 0; ks < 2; ++ks)
#pragma unroll
      for (int kb = 0; kb < 4; ++kb) {
        int row = kb * 16 + l16;
        bf16x8 bk = *(const bf16x8*)&Klds[row * 64 + ((ks * 32 + lhi * 8) ^ swz)];
        accS[kb] = mfma16(aq[ks], bk, accS[kb]);
      }
    __builtin_amdgcn_s_setprio(0);

    // scores (exp2 domain); E gathered via in-wave shuffles
    float sc[4][4];
    float lm[4];
    bool need = false;
#pragma unroll
    for (int r = 0; r < 4; ++r) {
      int m = lhi * 4 + r;
      int srcl = lhi * 16 + ((l16 - m + 15) & 15);
      bool lo = (l16 <= m);
      float e[5];
#pragma unroll
      for (int c = 0; c < 5; ++c) e[c] = __shfl(accE[c][r], srcl);
#pragma unroll
      for (int kb = 0; kb < 4; ++kb) sc[r][kb] = accS[kb][r] + (lo ? e[kb] : e[kb + 1]);
      lm[r] = fmaxf(fmaxf(sc[r][0], sc[r][1]), fmaxf(sc[r][2], sc[r][3]));
      need |= (lm[r] > mrun[r] + THR);
    }
    // lazy max: full tree + rescale only when some lane's local max exceeds THR
    if (__ballot(need)) {
#pragma unroll
      for (int r = 0; r < 4; ++r) {
        float tm = lm[r];
        tm = fmaxf(tm, __shfl_xor(tm, 1));
        tm = fmaxf(tm, __shfl_xor(tm, 2));
        tm = fmaxf(tm, __shfl_xor(tm, 4));
        tm = fmaxf(tm, __shfl_xor(tm, 8));
        float mnew = fmaxf(mrun[r], tm);
        float al = exp2f(mrun[r] - mnew);
        mrun[r] = mnew;
        lsum[r] *= al;
#pragma unroll
        for (int dt = 0; dt < 4; ++dt) accO[dt][r] *= al;
      }
    }
#pragma unroll
    for (int r = 0; r < 4; ++r) {
      int m = lhi * 4 + r;
      int swm = (m & 7) << 3;
      float mm = mrun[r], ps = 0.0f;
#pragma unroll
      for (int kb = 0; kb < 4; ++kb) {
        float pv = exp2f(sc[r][kb] - mm);
        ps += pv;
        Plds[w][m * 64 + ((kb * 16 + l16) ^ swm)] = f2bf(pv);
      }
      lsum[r] += ps;  // per-lane partial; reduced once in epilogue
    }

    // PV: accO[dt] += P[16,64] @ V[64, dt*16..]
    __builtin_amdgcn_s_setprio(1);
#pragma unroll
    for (int ks = 0; ks < 2; ++ks) {
      bf16x8 ap = *(const bf16x8*)&Plds[w][l16 * 64 + ((ks * 32 + lhi * 8) ^ ((l16 & 7) << 3))];
#pragma unroll
      for (int dt = 0; dt < 4; ++dt) {
        int row = dt * 16 + l16;
        bf16x8 bv = *(const bf16x8*)&Vt[row * 64 + ((ks * 32 + lhi * 8) ^ swz)];
        accO[dt] = mfma16(ap, bv, accO[dt]);
      }
    }
    __builtin_amdgcn_s_setprio(0);
    __syncthreads();  // all waves done reading K/V/P of this tile
  }

  // epilogue: reduce l across the 16-lane row groups; write UNNORMALIZED
  // partials: pbuf[pidx][row][dh] (bf16), mlb[pidx][row] = {m, l}
  int pidx = cid * 2 + half;
#pragma unroll
  for (int r = 0; r < 4; ++r) {
    float l = lsum[r];
    l += __shfl_xor(l, 1);
    l += __shfl_xor(l, 2);
    l += __shfl_xor(l, 4);
    l += __shfl_xor(l, 8);
    lsum[r] = l;
  }
#pragma unroll
  for (int r = 0; r < 4; ++r) {
    int row = w * 16 + lhi * 4 + r;
    if (l16 == 0) {
      mlb[((size_t)pidx * 64 + row) * 2] = mrun[r];
      mlb[((size_t)pidx * 64 + row) * 2 + 1] = lsum[r];
    }
#pragma unroll
    for (int dt = 0; dt < 4; ++dt)
      pbuf[((size_t)pidx * 64 + row) * 64 + dt * 16 + l16] = f2bf(accO[dt][r]);
  }
}

// ---------------- combine the two KV-halves -> attnb [B*T, H*64] bf16 ----------------
__global__ __launch_bounds__(256) void combine_kernel(const u16* __restrict__ pbuf,
                                                      const float* __restrict__ mlb,
                                                      u16* __restrict__ attnb) {
  int cid = blockIdx.x;
  int qb = cid & 31, h = (cid >> 5) & 15, b = cid >> 9;
  int tid = threadIdx.x;
  int row = tid >> 2, qd = (tid & 3) * 16;
  size_t base0 = ((size_t)(cid * 2) * 64 + row) * 64 + qd;
  size_t base1 = base0 + 4096;
  const float* m0 = mlb + ((size_t)(cid * 2) * 64 + row) * 2;
  float m1 = m0[0], l1 = m0[1], m2 = m0[128], l2 = m0[129];
  float mm = fmaxf(m1, m2);
  float a1 = exp2f(m1 - mm), a2 = exp2f(m2 - mm);
  float inv = 1.0f / (a1 * l1 + a2 * l2);
  a1 *= inv;
  a2 *= inv;
  uint4 x[2], y[2];
  x[0] = *(const uint4*)&pbuf[base0];
  x[1] = *(const uint4*)&pbuf[base0 + 8];
  y[0] = *(const uint4*)&pbuf[base1];
  y[1] = *(const uint4*)&pbuf[base1 + 8];
  uint4 o[2];
#pragma unroll
  for (int v = 0; v < 2; ++v) {
    unsigned* xu = (unsigned*)&x[v];
    unsigned* yu = (unsigned*)&y[v];
    unsigned* ou = (unsigned*)&o[v];
#pragma unroll
    for (int j = 0; j < 4; ++j) {
      float f0 = bf2f((u16)(xu[j] & 0xffff)), f1 = bf2f((u16)(xu[j] >> 16));
      float g0 = bf2f((u16)(yu[j] & 0xffff)), g1 = bf2f((u16)(yu[j] >> 16));
      ou[j] = (unsigned)f2bf(f0 * a1 + g0 * a2) | ((unsigned)f2bf(f1 * a1 + g1 * a2) << 16);
    }
  }
  size_t dst = ((size_t)(b * 2048 + qb * 64 + row)) * 1024 + h * 64 + qd;
  *(uint4*)&attnb[dst] = o[0];
  *(uint4*)&attnb[dst + 8] = o[1];
}

extern "C" void kernel_launch(void* const* d_in, const int* in_sizes, int n_in,
                              void* d_out, int out_size, void* d_ws, size_t ws_size,
                              hipStream_t stream) {
  const float* x = (const float*)d_in[0];
  const float* ctx = (const float*)d_in[1];
  const float* Ltab = (const float*)d_in[2];
  const float* Wq = (const float*)d_in[3];
  const float* Wk = (const float*)d_in[4];
  const float* Wv = (const float*)d_in[5];
  const float* Wo = (const float*)d_in[6];
  const float* bo = (const float*)d_in[7];
  const float* gamma = (const float*)d_in[8];
  const float* beta = (const float*)d_in[9];
  float* out = (float*)d_out;

  size_t off = 0;
  auto take = [&](size_t bytes) {
    void* p = (char*)d_ws + off;
    off += (bytes + 255) & ~(size_t)255;
    return p;
  };
  u16* xnb = (u16*)take(8388608);    // xn bf16 [4096,1024]
  u16* ctxb = (u16*)take(8388608);   // context bf16
  u16* Lb = (u16*)take(4095 * 64 * 2);
  u16* Wall = (u16*)take(4 * 2097152);  // Wq',Wk',Wv,Wo transposed bf16
  u16* qbuf = (u16*)take(8388608);   // [B,H,T,64]
  u16* kbuf = (u16*)take(8388608);   // [B,H,S,64]
  u16* vtbuf = (u16*)take(8388608);  // [B,H,64,S]
  u16* attnb = (u16*)take(8388608);  // [B*T, 1024]
  float* mlb = (float*)take(2048 * 64 * 2 * 4);  // per (half, row): m, l
  // partial O (bf16, 2048*64*64*2 = 16.78 MB) overlays xnb+ctxb (dead by then)
  u16* pbuf = xnb;

  ln_kernel<<<dim3(4096), dim3(256), 0, stream>>>(x, gamma, beta, out, xnb);
  cvt_kernel<<<dim3(4096), dim3(256), 0, stream>>>(ctx, ctxb, 1048576);
  cvt_kernel<<<dim3(256), dim3(256), 0, stream>>>(Ltab, Lb, 65520);
  transW_kernel<<<dim3(32, 32, 4), dim3(32, 8), 0, stream>>>(Wq, Wk, Wv, Wo, Wall);
  qkv_kernel<<<dim3(32, 16, 3), dim3(256), 0, stream>>>(xnb, ctxb, Wall, qbuf, kbuf, vtbuf);
  flash_kernel<<<dim3(2048), dim3(256), 0, stream>>>(qbuf, kbuf, vtbuf, Lb, pbuf, mlb);
  combine_kernel<<<dim3(1024), dim3(256), 0, stream>>>(pbuf, mlb, attnb);
  oproj_kernel<<<dim3(32, 16), dim3(256), 0, stream>>>(attnb, Wall, bo, out, out);
}

// Round 7
// 227.146 us; speedup vs baseline: 1.8249x; 1.8249x over previous
//
#include <hip/hip_runtime.h>

#define DEVFN __device__ __forceinline__

typedef __bf16 bf16x8 __attribute__((ext_vector_type(8)));
typedef float f32x4 __attribute__((ext_vector_type(4)));
typedef unsigned short u16;

// B=2, T=S=2048, D=1024, H=16, DH=64
// Scales folded into weights: Wq *= 0.125*log2(e), Wk *= 0.125  =>
// score_log2e = q'.k' + q'.L  ; softmax done in exp2 domain.

DEVFN u16 f2bf(float f) {
  unsigned u = __builtin_bit_cast(unsigned, f);
  u += 0x7FFFu + ((u >> 16) & 1u);
  return (u16)(u >> 16);
}

DEVFN float bf2f(u16 v) {
  return __builtin_bit_cast(float, (unsigned)v << 16);
}

DEVFN f32x4 mfma16(bf16x8 a, bf16x8 b, f32x4 c) {
  return __builtin_amdgcn_mfma_f32_16x16x32_bf16(a, b, c, 0, 0, 0);
}

DEVFN void gl16(const u16* g, u16* l) {
  __builtin_amdgcn_global_load_lds(
      (const __attribute__((address_space(1))) unsigned int*)g,
      (__attribute__((address_space(3))) unsigned int*)l, 16, 0, 0);
}

// ---------------- LayerNorm: x[4096,1024] -> xn (f32, into d_out) + xn bf16 ----------------
__global__ __launch_bounds__(256) void ln_kernel(const float* __restrict__ x,
                                                 const float* __restrict__ gamma,
                                                 const float* __restrict__ beta,
                                                 float* __restrict__ xn,
                                                 u16* __restrict__ xnb) {
  int row = blockIdx.x;
  int tid = threadIdx.x;
  const float4* xr = (const float4*)(x + (size_t)row * 1024);
  float4 v = xr[tid];
  float s = v.x + v.y + v.z + v.w;
  float q = v.x * v.x + v.y * v.y + v.z * v.z + v.w * v.w;
#pragma unroll
  for (int m = 1; m < 64; m <<= 1) {
    s += __shfl_xor(s, m);
    q += __shfl_xor(q, m);
  }
  __shared__ float rs[4], rq[4];
  int w = tid >> 6;
  if ((tid & 63) == 0) { rs[w] = s; rq[w] = q; }
  __syncthreads();
  s = rs[0] + rs[1] + rs[2] + rs[3];
  q = rq[0] + rq[1] + rq[2] + rq[3];
  float mean = s * (1.0f / 1024.0f);
  float var = q * (1.0f / 1024.0f) - mean * mean;
  float inv = rsqrtf(var + 1e-5f);
  float4 g = ((const float4*)gamma)[tid];
  float4 bt = ((const float4*)beta)[tid];
  float4 o;
  o.x = (v.x - mean) * inv * g.x + bt.x;
  o.y = (v.y - mean) * inv * g.y + bt.y;
  o.z = (v.z - mean) * inv * g.z + bt.z;
  o.w = (v.w - mean) * inv * g.w + bt.w;
  ((float4*)(xn + (size_t)row * 1024))[tid] = o;
  ushort4 ob;
  ob.x = f2bf(o.x); ob.y = f2bf(o.y); ob.z = f2bf(o.z); ob.w = f2bf(o.w);
  ((ushort4*)(xnb + (size_t)row * 1024))[tid] = ob;
}

// ---------------- f32 -> bf16 convert (vectorized by 4) ----------------
__global__ __launch_bounds__(256) void cvt_kernel(const float* __restrict__ in,
                                                  u16* __restrict__ out, int n4) {
  int i = blockIdx.x * 256 + threadIdx.x;
  if (i < n4) {
    float4 v = ((const float4*)in)[i];
    ushort4 o;
    o.x = f2bf(v.x); o.y = f2bf(v.y); o.z = f2bf(v.z); o.w = f2bf(v.w);
    ((ushort4*)out)[i] = o;
  }
}

// ---------------- 4x W [1024,1024] f32 -> Wall[z] bf16 transposed (scaled) ----------------
__global__ __launch_bounds__(256) void transW_kernel(const float* __restrict__ W0,
                                                     const float* __restrict__ W1,
                                                     const float* __restrict__ W2,
                                                     const float* __restrict__ W3,
                                                     u16* __restrict__ Wall) {
  __shared__ float tile[32][33];
  int z = blockIdx.z;
  const float* W = (z == 0) ? W0 : (z == 1) ? W1 : (z == 2) ? W2 : W3;
  float scale = (z == 0) ? 0.18033688011112042f : (z == 1) ? 0.125f : 1.0f;
  u16* Wt = Wall + (size_t)z * 1048576;
  int tx = threadIdx.x, ty = threadIdx.y;
  int x = blockIdx.x * 32 + tx;
  int y0 = blockIdx.y * 32;
#pragma unroll
  for (int j = 0; j < 32; j += 8)
    tile[ty + j][tx] = W[(size_t)(y0 + ty + j) * 1024 + x];
  __syncthreads();
#pragma unroll
  for (int j = 0; j < 32; j += 8)
    Wt[(size_t)(blockIdx.x * 32 + ty + j) * 1024 + y0 + tx] = f2bf(tile[tx][ty + j] * scale);
}

// ---------------- shared GEMM core: 128x64 tile, K=1024, gload_lds + XOR swizzle ----------------
DEVFN void gemm_core(const u16* __restrict__ A, const u16* __restrict__ Bt,
                     u16* Ab, u16* Bb, int row0, int n0, int tid,
                     f32x4 (&acc)[2][4]) {
  int lane = tid & 63, wv = tid >> 6;
  int l16 = lane & 15, lhi = lane >> 4;
  int r8 = lane >> 3, c8 = lane & 7;
  int cx = ((c8 ^ r8) << 3);           // pre-swizzled source column (elements)
  int swz = (l16 & 7) << 3;            // read-side XOR (elements)

  auto stage = [&](int k0) {
#pragma unroll
    for (int i = 0; i < 4; ++i) {
      int rowb = wv * 32 + i * 8;
      gl16(&A[(size_t)(row0 + rowb + r8) * 1024 + k0 + cx], &Ab[rowb * 64]);
    }
#pragma unroll
    for (int i = 0; i < 2; ++i) {
      int rowb = wv * 16 + i * 8;
      gl16(&Bt[(size_t)(n0 + rowb + r8) * 1024 + k0 + cx], &Bb[rowb * 64]);
    }
  };

  stage(0);
  asm volatile("s_waitcnt vmcnt(0)" ::: "memory");
  __syncthreads();
  for (int kk = 0; kk < 16; ++kk) {
    __builtin_amdgcn_s_setprio(1);
#pragma unroll
    for (int ks = 0; ks < 2; ++ks) {
      bf16x8 af[2], bfr[4];
#pragma unroll
      for (int mi = 0; mi < 2; ++mi) {
        int row = wv * 32 + mi * 16 + l16;
        af[mi] = *(const bf16x8*)&Ab[row * 64 + ((ks * 32 + lhi * 8) ^ swz)];
      }
#pragma unroll
      for (int ni = 0; ni < 4; ++ni) {
        int row = ni * 16 + l16;
        bfr[ni] = *(const bf16x8*)&Bb[row * 64 + ((ks * 32 + lhi * 8) ^ swz)];
      }
#pragma unroll
      for (int mi = 0; mi < 2; ++mi)
#pragma unroll
        for (int ni = 0; ni < 4; ++ni)
          acc[mi][ni] = mfma16(af[mi], bfr[ni], acc[mi][ni]);
    }
    __builtin_amdgcn_s_setprio(0);
    if (kk < 15) {
      __syncthreads();
      stage((kk + 1) * 64);
      asm volatile("s_waitcnt vmcnt(0)" ::: "memory");
      __syncthreads();
    }
  }
}

// ---------------- QKV projections in one launch (z = 0,1,2) ----------------
// z=0: Q = xn@Wq' -> [B,H,T,64]; z=1: K -> [B,H,S,64]; z=2: V -> [B,H,64,S] (transposed!)
__global__ __launch_bounds__(256, 4) void qkv_kernel(const u16* __restrict__ xnb,
                                                     const u16* __restrict__ ctxb,
                                                     const u16* __restrict__ Wall,
                                                     u16* __restrict__ qb,
                                                     u16* __restrict__ kb,
                                                     u16* __restrict__ vtb) {
  __shared__ __align__(16) u16 Ab[128 * 64];
  __shared__ __align__(16) u16 Bb[64 * 64];
  int z = blockIdx.z;
  const u16* A = (z == 0) ? xnb : ctxb;
  const u16* Bt = Wall + (size_t)z * 1048576;
  int row0 = blockIdx.x * 128, n0 = blockIdx.y * 64;
  f32x4 acc[2][4] = {};
  gemm_core(A, Bt, Ab, Bb, row0, n0, threadIdx.x, acc);
  int tid = threadIdx.x, lane = tid & 63, wv = tid >> 6;
  int l16 = lane & 15, lhi = lane >> 4;
  u16* qk = (z == 0) ? qb : kb;
#pragma unroll
  for (int mi = 0; mi < 2; ++mi)
#pragma unroll
    for (int ni = 0; ni < 4; ++ni)
#pragma unroll
      for (int r = 0; r < 4; ++r) {
        int m = row0 + wv * 32 + mi * 16 + lhi * 4 + r;
        int n = n0 + ni * 16 + l16;
        int b = m >> 11, t = m & 2047, h = n >> 6, dh = n & 63;
        u16 val = f2bf(acc[mi][ni][r]);
        if (z < 2)
          qk[(size_t)((b * 16 + h) * 2048 + t) * 64 + dh] = val;
        else
          vtb[(size_t)((b * 16 + h) * 64 + dh) * 2048 + t] = val;
      }
}

// ---------------- output projection + bias + residual ----------------
__global__ __launch_bounds__(256, 4) void oproj_kernel(const u16* __restrict__ attnb,
                                                       const u16* __restrict__ Wall,
                                                       const float* __restrict__ bias,
                                                       const float* __restrict__ resid,
                                                       float* __restrict__ outF) {
  __shared__ __align__(16) u16 Ab[128 * 64];
  __shared__ __align__(16) u16 Bb[64 * 64];
  const u16* Bt = Wall + (size_t)3 * 1048576;
  int row0 = blockIdx.x * 128, n0 = blockIdx.y * 64;
  f32x4 acc[2][4] = {};
  gemm_core(attnb, Bt, Ab, Bb, row0, n0, threadIdx.x, acc);
  int tid = threadIdx.x, lane = tid & 63, wv = tid >> 6;
  int l16 = lane & 15, lhi = lane >> 4;
#pragma unroll
  for (int mi = 0; mi < 2; ++mi)
#pragma unroll
    for (int ni = 0; ni < 4; ++ni)
#pragma unroll
      for (int r = 0; r < 4; ++r) {
        int m = row0 + wv * 32 + mi * 16 + lhi * 4 + r;
        int n = n0 + ni * 16 + l16;
        outF[(size_t)m * 1024 + n] = acc[mi][ni][r] + bias[n] + resid[(size_t)m * 1024 + n];
      }
}

// ---------------- flash attention, KV-split x2 (flash-decoding) ----------------
// Qg,Kg: [B,H,2048,64] bf16 (scaled). Vtg: [B,H,64,2048] bf16. Lb: [4095,64] bf16.
// Each block: 64 q-rows, 16 KV tiles (1024 keys). Writes UNNORMALIZED O (bf16)
// + per-row (m, l) to pbuf/mlb; combine_kernel merges the two halves.
// launch_bounds (256,4): VGPR cap 128 (kernel needs ~64; the (256,6) cap at 40
// caused 459 MB of scratch spill in r6). Residency is LDS-limited: 24 KB -> 6
// blocks/CU = 24 waves/CU anyway.
__global__ __launch_bounds__(256, 4) void flash_kernel(
    const u16* __restrict__ Qg, const u16* __restrict__ Kg,
    const u16* __restrict__ Vtg, const u16* __restrict__ Lb,
    u16* __restrict__ pbuf, float* __restrict__ mlb) {
  constexpr int T = 2048, H = 16;
  int p = blockIdx.x;
  int bid = (p & 7) * 256 + (p >> 3);  // XCD-contiguous mapping (grid=2048, 8 XCDs)
  int half = bid & 1;
  int cid = bid >> 1;
  int qb = cid & 31, h = (cid >> 5) & 15, b = cid >> 9;
  int st = half * 16;  // first KV tile index
  int tid = threadIdx.x;
  int lane = tid & 63, w = tid >> 6;
  int l16 = lane & 15, lhi = lane >> 4;

  __shared__ __align__(16) u16 Klds[64 * 64];     // 8 KB
  __shared__ __align__(16) u16 Vt[64 * 64];       // 8 KB
  __shared__ __align__(16) u16 Plds[4][16 * 64];  // 8 KB (XOR-swizzled)

  const u16* qbase = Qg + (size_t)(b * H + h) * T * 64;
  const u16* kbase = Kg + (size_t)(b * H + h) * T * 64;
  const u16* vtbase = Vtg + (size_t)(b * H + h) * 64 * 2048;

  int i0w = qb * 64 + w * 16;
  bf16x8 aq[2];
  aq[0] = *(const bf16x8*)&qbase[(i0w + l16) * 64 + lhi * 8];
  aq[1] = *(const bf16x8*)&qbase[(i0w + l16) * 64 + 32 + lhi * 8];

  f32x4 accO[4] = {};
  float mrun[4], lsum[4];
#pragma unroll
  for (int r = 0; r < 4; ++r) { mrun[r] = -1e30f; lsum[r] = 0.0f; }

  int bandbase = T - 16 - i0w;

  int r8 = lane >> 3, c8 = lane & 7;
  int cx = ((c8 ^ r8) << 3);
  int swz = (l16 & 7) << 3;

  auto stage = [&](int j0) {
#pragma unroll
    for (int i = 0; i < 2; ++i) {
      int rowb = w * 16 + i * 8;
      gl16(&kbase[(size_t)(j0 + rowb + r8) * 64 + cx], &Klds[rowb * 64]);
    }
#pragma unroll
    for (int i = 0; i < 2; ++i) {
      int rowb = w * 16 + i * 8;
      gl16(&vtbase[(size_t)(rowb + r8) * 2048 + j0 + cx], &Vt[rowb * 64]);
    }
  };

  // E-carry preamble: eC = E[., colE 0..15] of the first tile of this half
  f32x4 eC = {};
#pragma unroll
  for (int ks = 0; ks < 2; ++ks) {
    int u = bandbase + st * 64 + l16;
    u = min(max(u, 0), 2 * T - 2);
    bf16x8 bl = *(const bf16x8*)&Lb[(size_t)u * 64 + ks * 32 + lhi * 8];
    eC = mfma16(aq[ks], bl, eC);
  }

  const float THR = 11.541560327111707f;  // 8 * log2(e)

  for (int kt = st; kt < st + 16; ++kt) {
    int j0 = kt * 64, bstart = bandbase + j0;
    // issue stage for THIS tile, hide the drain under the E-term MFMAs
    stage(j0);

    f32x4 accE[5];
    accE[0] = eC;
#pragma unroll
    for (int c = 1; c < 5; ++c) accE[c] = f32x4{0.f, 0.f, 0.f, 0.f};
#pragma unroll
    for (int ks = 0; ks < 2; ++ks) {
      bf16x8 bl[4];
#pragma unroll
      for (int c = 1; c < 5; ++c) {
        int u = bstart + c * 16 + l16;
        u = min(max(u, 0), 2 * T - 2);
        bl[c - 1] = *(const bf16x8*)&Lb[(size_t)u * 64 + ks * 32 + lhi * 8];
      }
#pragma unroll
      for (int c = 1; c < 5; ++c) accE[c] = mfma16(aq[ks], bl[c - 1], accE[c]);
    }
    eC = accE[4];

    __syncthreads();  // drains vmcnt(0): gl16 latency mostly elapsed under E

    // QK^T
    f32x4 accS[4] = {};
    __builtin_amdgcn_s_setprio(1);
#pragma unroll
    for (int ks = 0; ks < 2; ++ks)
#pragma unroll
      for (int kb = 0; kb < 4; ++kb) {
        int row = kb * 16 + l16;
        bf16x8 bk = *(const bf16x8*)&Klds[row * 64 + ((ks * 32 + lhi * 8) ^ swz)];
        accS[kb] = mfma16(aq[ks], bk, accS[kb]);
      }
    __builtin_amdgcn_s_setprio(0);

    // scores (exp2 domain); E gathered via in-wave shuffles
    float sc[4][4];
    float lm[4];
    bool need = false;
#pragma unroll
    for (int r = 0; r < 4; ++r) {
      int m = lhi * 4 + r;
      int srcl = lhi * 16 + ((l16 - m + 15) & 15);
      bool lo = (l16 <= m);
      float e[5];
#pragma unroll
      for (int c = 0; c < 5; ++c) e[c] = __shfl(accE[c][r], srcl);
#pragma unroll
      for (int kb = 0; kb < 4; ++kb) sc[r][kb] = accS[kb][r] + (lo ? e[kb] : e[kb + 1]);
      lm[r] = fmaxf(fmaxf(sc[r][0], sc[r][1]), fmaxf(sc[r][2], sc[r][3]));
      need |= (lm[r] > mrun[r] + THR);
    }
    // lazy max: full tree + rescale only when some lane's local max exceeds THR
    if (__ballot(need)) {
#pragma unroll
      for (int r = 0; r < 4; ++r) {
        float tm = lm[r];
        tm = fmaxf(tm, __shfl_xor(tm, 1));
        tm = fmaxf(tm, __shfl_xor(tm, 2));
        tm = fmaxf(tm, __shfl_xor(tm, 4));
        tm = fmaxf(tm, __shfl_xor(tm, 8));
        float mnew = fmaxf(mrun[r], tm);
        float al = exp2f(mrun[r] - mnew);
        mrun[r] = mnew;
        lsum[r] *= al;
#pragma unroll
        for (int dt = 0; dt < 4; ++dt) accO[dt][r] *= al;
      }
    }
#pragma unroll
    for (int r = 0; r < 4; ++r) {
      int m = lhi * 4 + r;
      int swm = (m & 7) << 3;
      float mm = mrun[r], ps = 0.0f;
#pragma unroll
      for (int kb = 0; kb < 4; ++kb) {
        float pv = exp2f(sc[r][kb] - mm);
        ps += pv;
        Plds[w][m * 64 + ((kb * 16 + l16) ^ swm)] = f2bf(pv);
      }
      lsum[r] += ps;  // per-lane partial; reduced once in epilogue
    }

    // PV: accO[dt] += P[16,64] @ V[64, dt*16..]
    __builtin_amdgcn_s_setprio(1);
#pragma unroll
    for (int ks = 0; ks < 2; ++ks) {
      bf16x8 ap = *(const bf16x8*)&Plds[w][l16 * 64 + ((ks * 32 + lhi * 8) ^ ((l16 & 7) << 3))];
#pragma unroll
      for (int dt = 0; dt < 4; ++dt) {
        int row = dt * 16 + l16;
        bf16x8 bv = *(const bf16x8*)&Vt[row * 64 + ((ks * 32 + lhi * 8) ^ swz)];
        accO[dt] = mfma16(ap, bv, accO[dt]);
      }
    }
    __builtin_amdgcn_s_setprio(0);
    __syncthreads();  // all waves done reading K/V/P of this tile
  }

  // epilogue: reduce l across the 16-lane row groups; write UNNORMALIZED
  // partials: pbuf[pidx][row][dh] (bf16), mlb[pidx][row] = {m, l}
  int pidx = cid * 2 + half;
#pragma unroll
  for (int r = 0; r < 4; ++r) {
    float l = lsum[r];
    l += __shfl_xor(l, 1);
    l += __shfl_xor(l, 2);
    l += __shfl_xor(l, 4);
    l += __shfl_xor(l, 8);
    lsum[r] = l;
  }
#pragma unroll
  for (int r = 0; r < 4; ++r) {
    int row = w * 16 + lhi * 4 + r;
    if (l16 == 0) {
      mlb[((size_t)pidx * 64 + row) * 2] = mrun[r];
      mlb[((size_t)pidx * 64 + row) * 2 + 1] = lsum[r];
    }
#pragma unroll
    for (int dt = 0; dt < 4; ++dt)
      pbuf[((size_t)pidx * 64 + row) * 64 + dt * 16 + l16] = f2bf(accO[dt][r]);
  }
}

// ---------------- combine the two KV-halves -> attnb [B*T, H*64] bf16 ----------------
__global__ __launch_bounds__(256) void combine_kernel(const u16* __restrict__ pbuf,
                                                      const float* __restrict__ mlb,
                                                      u16* __restrict__ attnb) {
  int cid = blockIdx.x;
  int qb = cid & 31, h = (cid >> 5) & 15, b = cid >> 9;
  int tid = threadIdx.x;
  int row = tid >> 2, qd = (tid & 3) * 16;
  size_t base0 = ((size_t)(cid * 2) * 64 + row) * 64 + qd;
  size_t base1 = base0 + 4096;
  const float* m0 = mlb + ((size_t)(cid * 2) * 64 + row) * 2;
  float m1 = m0[0], l1 = m0[1], m2 = m0[128], l2 = m0[129];
  float mm = fmaxf(m1, m2);
  float a1 = exp2f(m1 - mm), a2 = exp2f(m2 - mm);
  float inv = 1.0f / (a1 * l1 + a2 * l2);
  a1 *= inv;
  a2 *= inv;
  uint4 x[2], y[2];
  x[0] = *(const uint4*)&pbuf[base0];
  x[1] = *(const uint4*)&pbuf[base0 + 8];
  y[0] = *(const uint4*)&pbuf[base1];
  y[1] = *(const uint4*)&pbuf[base1 + 8];
  uint4 o[2];
#pragma unroll
  for (int v = 0; v < 2; ++v) {
    unsigned* xu = (unsigned*)&x[v];
    unsigned* yu = (unsigned*)&y[v];
    unsigned* ou = (unsigned*)&o[v];
#pragma unroll
    for (int j = 0; j < 4; ++j) {
      float f0 = bf2f((u16)(xu[j] & 0xffff)), f1 = bf2f((u16)(xu[j] >> 16));
      float g0 = bf2f((u16)(yu[j] & 0xffff)), g1 = bf2f((u16)(yu[j] >> 16));
      ou[j] = (unsigned)f2bf(f0 * a1 + g0 * a2) | ((unsigned)f2bf(f1 * a1 + g1 * a2) << 16);
    }
  }
  size_t dst = ((size_t)(b * 2048 + qb * 64 + row)) * 1024 + h * 64 + qd;
  *(uint4*)&attnb[dst] = o[0];
  *(uint4*)&attnb[dst + 8] = o[1];
}

extern "C" void kernel_launch(void* const* d_in, const int* in_sizes, int n_in,
                              void* d_out, int out_size, void* d_ws, size_t ws_size,
                              hipStream_t stream) {
  const float* x = (const float*)d_in[0];
  const float* ctx = (const float*)d_in[1];
  const float* Ltab = (const float*)d_in[2];
  const float* Wq = (const float*)d_in[3];
  const float* Wk = (const float*)d_in[4];
  const float* Wv = (const float*)d_in[5];
  const float* Wo = (const float*)d_in[6];
  const float* bo = (const float*)d_in[7];
  const float* gamma = (const float*)d_in[8];
  const float* beta = (const float*)d_in[9];
  float* out = (float*)d_out;

  size_t off = 0;
  auto take = [&](size_t bytes) {
    void* p = (char*)d_ws + off;
    off += (bytes + 255) & ~(size_t)255;
    return p;
  };
  u16* xnb = (u16*)take(8388608);    // xn bf16 [4096,1024]
  u16* ctxb = (u16*)take(8388608);   // context bf16
  u16* Lb = (u16*)take(4095 * 64 * 2);
  u16* Wall = (u16*)take(4 * 2097152);  // Wq',Wk',Wv,Wo transposed bf16
  u16* qbuf = (u16*)take(8388608);   // [B,H,T,64]
  u16* kbuf = (u16*)take(8388608);   // [B,H,S,64]
  u16* vtbuf = (u16*)take(8388608);  // [B,H,64,S]
  u16* attnb = (u16*)take(8388608);  // [B*T, 1024]
  float* mlb = (float*)take(2048 * 64 * 2 * 4);  // per (half, row): m, l
  // partial O (bf16, 2048*64*64*2 = 16.78 MB) overlays xnb+ctxb (dead by then)
  u16* pbuf = xnb;

  ln_kernel<<<dim3(4096), dim3(256), 0, stream>>>(x, gamma, beta, out, xnb);
  cvt_kernel<<<dim3(4096), dim3(256), 0, stream>>>(ctx, ctxb, 1048576);
  cvt_kernel<<<dim3(256), dim3(256), 0, stream>>>(Ltab, Lb, 65520);
  transW_kernel<<<dim3(32, 32, 4), dim3(32, 8), 0, stream>>>(Wq, Wk, Wv, Wo, Wall);
  qkv_kernel<<<dim3(32, 16, 3), dim3(256), 0, stream>>>(xnb, ctxb, Wall, qbuf, kbuf, vtbuf);
  flash_kernel<<<dim3(2048), dim3(256), 0, stream>>>(qbuf, kbuf, vtbuf, Lb, pbuf, mlb);
  combine_kernel<<<dim3(1024), dim3(256), 0, stream>>>(pbuf, mlb, attnb);
  oproj_kernel<<<dim3(32, 16), dim3(256), 0, stream>>>(attnb, Wall, bo, out, out);
}